// Round 14
// baseline (629.166 us; speedup 1.0000x reference)
//
#include <hip/hip_runtime.h>
#include <math.h>

#define B_   8
#define C_   32
#define H_   512
#define W_   512
#define CQ_  8
#define NW_  4096          // windows per batch
#define ED_  2048
#define EH_  1024
#define EPS_ 1e-6f

__device__ __forceinline__ float leaky(float x) { return x > 0.f ? x : 0.1f * x; }
__device__ __forceinline__ float sigmoidf_(float x) { return 1.f / (1.f + __expf(-x)); }

// ---------------------------------------------------------------------------
// Pass A: inline-asm load pipeline, DEPTH 8 (8 x global_load_dwordx4 in
// flight per wave = 8 KB). r13's depth-16 failed correctness: ~190 VGPR of
// pressure made the allocator live-range-split the in-flight asm outputs
// (v_mov copies execute before the load lands -> garbage). Depth 8 needs
// ~130 VGPR << 256 cap -> no splits, and 4 waves/SIMD double the wave count:
// 16 waves/CU x 8 KB = 128 KB/CU in flight. Counted literal vmcnt paces
// consumption (in-order retire, m135); rule #18 sched_barrier(0) after each
// wait fences the consuming FMAs. Weights in LDS (r10). Geometry r9:
// wave = 8x32 strip, 4 px/thread, grid (4,64,8) = 2048 blocks.
// Channel order + per-q FMA chains bit-identical to r10 -> identical var.
// ---------------------------------------------------------------------------
__global__ __launch_bounds__(256, 2) void pass_a(
    const float* __restrict__ x,
    const float* __restrict__ w_in, const float* __restrict__ b_in,
    const float* __restrict__ w_conv, const float* __restrict__ b_conv,
    const float* __restrict__ ln_w, const float* __restrict__ ln_b,
    float* __restrict__ xq_out,                 // [B][CQ][H][W] scratch
    double* __restrict__ var_out,
    float* __restrict__ pooled_part)
{
    __shared__ float2 s_w[CQ_ * C_];         // (w_conv, w_in), 2 KB
    __shared__ float  red[4][CQ_];

    const int tid  = threadIdx.x;
    const int lane = tid & 63, wv = tid >> 6;
    const int sx   = blockIdx.x;             // cols [sx*128 .. +128), sx<4
    const int band = blockIdx.y;             // 0..63
    const int b    = blockIdx.z;
    const size_t plane = (size_t)H_ * W_;
    const float* xb = x + (size_t)b * C_ * plane;

    s_w[tid] = make_float2(w_conv[tid], w_in[tid]);   // [q*C + c] layout

    const int row0 = band * 8 + (lane >> 3);
    const int col0 = sx * 128 + wv * 32 + (lane & 7) * 4;   // <= 508
    const float* gp = xb + (size_t)row0 * W_ + col0;

    float ycv[CQ_][4], yin[CQ_][4];
#pragma unroll
    for (int q = 0; q < CQ_; ++q)
#pragma unroll
        for (int j = 0; j < 4; ++j) { ycv[q][j] = 0.f; yin[q][j] = 0.f; }

    __syncthreads();   // weights visible; vmcnt drained (barrier) before asm

#define GLOAD(reg, c)                                                      \
    asm volatile("global_load_dwordx4 %0, %1, off"                         \
                 : "=v"(reg) : "v"(gp + (size_t)(c) * plane) : "memory");

#define WFMA(reg, n, c)                                                    \
    asm volatile("s_waitcnt vmcnt(" #n ")" ::: "memory");                  \
    __builtin_amdgcn_sched_barrier(0);                                     \
    {                                                                      \
        _Pragma("unroll")                                                  \
        for (int q = 0; q < CQ_; ++q) {                                    \
            const float2 w = s_w[q * C_ + (c)];                            \
            ycv[q][0] = fmaf(w.x, (reg).x, ycv[q][0]);                     \
            ycv[q][1] = fmaf(w.x, (reg).y, ycv[q][1]);                     \
            ycv[q][2] = fmaf(w.x, (reg).z, ycv[q][2]);                     \
            ycv[q][3] = fmaf(w.x, (reg).w, ycv[q][3]);                     \
            yin[q][0] = fmaf(w.y, (reg).x, yin[q][0]);                     \
            yin[q][1] = fmaf(w.y, (reg).y, yin[q][1]);                     \
            yin[q][2] = fmaf(w.y, (reg).z, yin[q][2]);                     \
            yin[q][3] = fmaf(w.y, (reg).w, yin[q][3]);                     \
        }                                                                  \
    }

    float4 L0, L1, L2, L3, L4, L5, L6, L7;

    GLOAD(L0, 0) GLOAD(L1, 1) GLOAD(L2, 2) GLOAD(L3, 3)
    GLOAD(L4, 4) GLOAD(L5, 5) GLOAD(L6, 6) GLOAD(L7, 7)

    WFMA(L0, 7, 0)   GLOAD(L0, 8)
    WFMA(L1, 7, 1)   GLOAD(L1, 9)
    WFMA(L2, 7, 2)   GLOAD(L2, 10)
    WFMA(L3, 7, 3)   GLOAD(L3, 11)
    WFMA(L4, 7, 4)   GLOAD(L4, 12)
    WFMA(L5, 7, 5)   GLOAD(L5, 13)
    WFMA(L6, 7, 6)   GLOAD(L6, 14)
    WFMA(L7, 7, 7)   GLOAD(L7, 15)
    WFMA(L0, 7, 8)   GLOAD(L0, 16)
    WFMA(L1, 7, 9)   GLOAD(L1, 17)
    WFMA(L2, 7, 10)  GLOAD(L2, 18)
    WFMA(L3, 7, 11)  GLOAD(L3, 19)
    WFMA(L4, 7, 12)  GLOAD(L4, 20)
    WFMA(L5, 7, 13)  GLOAD(L5, 21)
    WFMA(L6, 7, 14)  GLOAD(L6, 22)
    WFMA(L7, 7, 15)  GLOAD(L7, 23)
    WFMA(L0, 7, 16)  GLOAD(L0, 24)
    WFMA(L1, 7, 17)  GLOAD(L1, 25)
    WFMA(L2, 7, 18)  GLOAD(L2, 26)
    WFMA(L3, 7, 19)  GLOAD(L3, 27)
    WFMA(L4, 7, 20)  GLOAD(L4, 28)
    WFMA(L5, 7, 21)  GLOAD(L5, 29)
    WFMA(L6, 7, 22)  GLOAD(L6, 30)
    WFMA(L7, 7, 23)  GLOAD(L7, 31)

    WFMA(L0, 7, 24)
    WFMA(L1, 6, 25)
    WFMA(L2, 5, 26)
    WFMA(L3, 4, 27)
    WFMA(L4, 3, 28)
    WFMA(L5, 2, 29)
    WFMA(L6, 1, 30)
    WFMA(L7, 0, 31)

#undef GLOAD
#undef WFMA

    // ---- bias, LN, leaky (identical order -> identical var bits) ----
#pragma unroll
    for (int q = 0; q < CQ_; ++q) {
        const float bc = b_conv[q];
#pragma unroll
        for (int j = 0; j < 4; ++j) ycv[q][j] += bc;
    }

    float ps[CQ_];
#pragma unroll
    for (int q = 0; q < CQ_; ++q) ps[q] = 0.f;

    float xmv[4];
#pragma unroll
    for (int j = 0; j < 4; ++j) {
        float u = 0.f;
#pragma unroll
        for (int q = 0; q < CQ_; ++q) u += ycv[q][j];
        u *= 0.125f;
        float s = 0.f;
#pragma unroll
        for (int q = 0; q < CQ_; ++q) { const float d = ycv[q][j] - u; s = fmaf(d, d, s); }
        s *= 0.125f;
        const float inv = 1.f / sqrtf(s + EPS_);
        float m = 0.f;
#pragma unroll
        for (int q = 0; q < CQ_; ++q) {
            const float xv = leaky(fmaf(ln_w[q], (ycv[q][j] - u) * inv, ln_b[q]));
            ycv[q][j] = xv;          // now holds x_
            ps[q] += xv;
            m += leaky(yin[q][j] + b_in[q]);
        }
        xmv[j] = m * 0.125f;
    }

    // ---- store x_ to global (float4 per channel) ----
#pragma unroll
    for (int q = 0; q < CQ_; ++q) {
        *reinterpret_cast<float4*>(
            &xq_out[(((size_t)b * CQ_ + q) * H_ + row0) * W_ + col0]) =
            make_float4(ycv[q][0], ycv[q][1], ycv[q][2], ycv[q][3]);
    }

    // ---- window variance, fully in-register (ddof=1, double) ----
    {
        double s = (double)xmv[0] + (double)xmv[1] + (double)xmv[2] + (double)xmv[3];
        s += __shfl_xor(s, 1);
        s += __shfl_xor(s, 8);
        s += __shfl_xor(s, 16);
        s += __shfl_xor(s, 32);
        const double mean = s * (1.0 / 64.0);
        double s2 = 0.0;
#pragma unroll
        for (int j = 0; j < 4; ++j) {
            const double d = (double)xmv[j] - mean;
            s2 += d * d;
        }
        s2 += __shfl_xor(s2, 1);
        s2 += __shfl_xor(s2, 8);
        s2 += __shfl_xor(s2, 16);
        s2 += __shfl_xor(s2, 32);
        if ((lane >> 3) == 0 && (lane & 1) == 0) {          // lanes 0,2,4,6
            const int k = (lane & 7) >> 1;
            const int n = band * 64 + sx * 16 + wv * 4 + k; // <= 4095
            var_out[(size_t)b * NW_ + n] = s2 * (1.0 / 63.0);
        }
    }

    // ---- pooled partials: wave reduce -> one store per block ----
#pragma unroll
    for (int q = 0; q < CQ_; ++q) {
        float s = ps[q];
#pragma unroll
        for (int off = 32; off; off >>= 1) s += __shfl_xor(s, off);
        if (lane == 0) red[wv][q] = s;
    }
    __syncthreads();
    if (tid < CQ_) {
        const float s = red[0][tid] + red[1][tid] + red[2][tid] + red[3][tid];
        const int bid = ((int)blockIdx.z * 64 + blockIdx.y) * 4 + blockIdx.x;
        pooled_part[bid * CQ_ + tid] = s;
    }
}

// ---------------------------------------------------------------------------
// SA: 3x3 conv over x_ (from global, L3-resident) + sigmoid.
// grid (8, 32, 8), block 256. LDS tile [8][18][72] with zero-padded halo.
// ---------------------------------------------------------------------------
__global__ __launch_bounds__(256) void sa_kernel(
    const float* __restrict__ xq,
    const float* __restrict__ w_sa, const float* __restrict__ b_sa,
    float* __restrict__ sa_out)
{
    __shared__ float xl[CQ_][18][72];
    const int tid = threadIdx.x;
    const int b = blockIdx.z;
    const int ty = blockIdx.y * 16, tx = blockIdx.x * 64;

    for (int idx = tid; idx < CQ_ * 18 * 18; idx += 256) {
        const int ch = idx / 324;
        const int rem = idx % 324;
        const int r = rem / 18, c4 = rem % 18;
        const int gy = ty + r - 1;
        const int gxf = tx + c4 * 4 - 4;
        float4 v = make_float4(0.f, 0.f, 0.f, 0.f);
        if (gy >= 0 && gy < H_ && gxf >= 0 && gxf < W_)
            v = *reinterpret_cast<const float4*>(
                    &xq[(((size_t)b * CQ_ + ch) * H_ + gy) * W_ + gxf]);
        *reinterpret_cast<float4*>(&xl[ch][r][c4 * 4]) = v;
    }
    __syncthreads();

    const int px = (tid & 15) * 4, py = tid >> 4;
    const float bsa = b_sa[0];
    float acc[4] = {bsa, bsa, bsa, bsa};
#pragma unroll
    for (int q = 0; q < CQ_; ++q) {
#pragma unroll
        for (int dy = 0; dy < 3; ++dy) {
            const float* r = &xl[q][py + dy][px];
            const float4 aa = *reinterpret_cast<const float4*>(r);
            const float4 bb = *reinterpret_cast<const float4*>(r + 4);
            const float4 cc = *reinterpret_cast<const float4*>(r + 8);
            const float a[12] = {aa.x, aa.y, aa.z, aa.w, bb.x, bb.y, bb.z, bb.w,
                                 cc.x, cc.y, cc.z, cc.w};
#pragma unroll
            for (int dx = 0; dx < 3; ++dx) {
                const float w = w_sa[q * 9 + dy * 3 + dx];
#pragma unroll
                for (int j = 0; j < 4; ++j) acc[j] = fmaf(w, a[j + 3 + dx], acc[j]);
            }
        }
    }
    const float4 o = make_float4(sigmoidf_(acc[0]), sigmoidf_(acc[1]),
                                 sigmoidf_(acc[2]), sigmoidf_(acc[3]));
    *reinterpret_cast<float4*>(&sa_out[((size_t)b * H_ + (ty + py)) * W_ + tx + px]) = o;
}

// ---------------------------------------------------------------------------
// K2 (fused tail): blocks 0..127 rank, 128..383 h1/h0, 384 CA.
// ---------------------------------------------------------------------------
__global__ __launch_bounds__(256) void k2_kernel(
    const double* __restrict__ var, float* __restrict__ maskF,
    const float* __restrict__ w_m1, const float* __restrict__ b_m1,
    float* __restrict__ h1, float* __restrict__ h0,
    const float* __restrict__ pooled_part,
    const float* __restrict__ w_ca, const float* __restrict__ b_ca,
    float* __restrict__ ca_out)
{
    __shared__ double sv[NW_];   // 32 KB
    const int bi = blockIdx.x;
    const int tid = threadIdx.x;

    if (bi < 128) {
        const int b = bi >> 4;
        const double* vb = var + (size_t)b * NW_;
        for (int j = tid; j < NW_; j += 256) sv[j] = vb[j];
        __syncthreads();
        const int i = (bi & 15) * 256 + tid;
        const double vi = sv[i];
        int cnt = 0;
#pragma unroll 4
        for (int j = 0; j < NW_; ++j) {
            const double vj = sv[j];
            cnt += (vj < vi) || (vj == vi && j < i);
        }
        maskF[(size_t)b * NW_ + i] = (cnt < NW_ / 2) ? 0.f : 1.f;
    } else if (bi < 384) {
        const int wave = tid >> 6, lane = tid & 63;
        const int e = (bi - 128) * 4 + wave;
        const float* row = w_m1 + (size_t)e * ED_;
        float s = 0.f;
#pragma unroll
        for (int k = 0; k < ED_ / 64; ++k) s += row[lane + 64 * k];
#pragma unroll
        for (int off = 32; off; off >>= 1) s += __shfl_xor(s, off);
        if (lane == 0) {
            h1[e] = leaky(s + b_m1[e]);
            h0[e] = leaky(b_m1[e]);
        }
    } else {
        float* sp = (float*)sv;
        const int bq = tid >> 2, part = tid & 3;
        const int bb = bq >> 3, q = bq & 7;
        float s = 0.f;
        for (int k = part; k < 256; k += 4)
            s += pooled_part[((size_t)bb * 256 + k) * CQ_ + q];
        sp[tid] = s;
        __syncthreads();
        if (tid < 64)
            sp[256 + tid] = (sp[4 * tid] + sp[4 * tid + 1] + sp[4 * tid + 2] + sp[4 * tid + 3])
                            * (1.f / ((float)H_ * (float)W_));
        __syncthreads();
        const int ob = tid >> 5, o = tid & 31;
        float acc = b_ca[o];
#pragma unroll
        for (int qq = 0; qq < CQ_; ++qq)
            acc = fmaf(w_ca[o * CQ_ + qq], sp[256 + ob * CQ_ + qq], acc);
        ca_out[tid] = sigmoidf_(acc);
    }
}

// ---------------------------------------------------------------------------
__global__ __launch_bounds__(256) void o_kernel(const float* __restrict__ w_m2,
                                                const float* __restrict__ b_m2,
                                                const float* __restrict__ h1,
                                                const float* __restrict__ h0,
                                                float* __restrict__ o1, float* __restrict__ o0)
{
    const int wave = threadIdx.x >> 6, lane = threadIdx.x & 63;
    const int f = blockIdx.x * 4 + wave;
    const float* row = w_m2 + (size_t)f * EH_;
    float s1 = 0.f, s0 = 0.f;
#pragma unroll
    for (int k = 0; k < EH_ / 64; ++k) {
        const float w = row[lane + 64 * k];
        s1 = fmaf(w, h1[lane + 64 * k], s1);
        s0 = fmaf(w, h0[lane + 64 * k], s0);
    }
#pragma unroll
    for (int off = 32; off; off >>= 1) {
        s1 += __shfl_xor(s1, off);
        s0 += __shfl_xor(s0, off);
    }
    if (lane == 0) {
        o1[f] = s1 + b_m2[f];
        o0[f] = s0 + b_m2[f];
    }
}

// ---------------------------------------------------------------------------
__global__ __launch_bounds__(256) void bcast_kernel(const float* __restrict__ maskF,
                                                    const float* __restrict__ o1,
                                                    const float* __restrict__ o0,
                                                    float* __restrict__ out)
{
    __shared__ float sm[16];
    const int t = threadIdx.x;
    const long row0 = (long)blockIdx.x * 16;
    if (t < 16) sm[t] = maskF[row0 + t];
    const float4 a1 = ((const float4*)o1)[t], b1 = ((const float4*)o1)[t + 256];
    const float4 a0 = ((const float4*)o0)[t], b0 = ((const float4*)o0)[t + 256];
    __syncthreads();
#pragma unroll
    for (int r = 0; r < 16; ++r) {
        float4* dst = (float4*)(out + (size_t)(row0 + r) * ED_);
        const bool m = sm[r] > 0.5f;
        dst[t]       = m ? a1 : a0;
        dst[t + 256] = m ? b1 : b0;
    }
}

extern "C" void kernel_launch(void* const* d_in, const int* in_sizes, int n_in,
                              void* d_out, int out_size, void* d_ws, size_t ws_size,
                              hipStream_t stream)
{
    const float* x    = (const float*)d_in[0];
    const float* w_in = (const float*)d_in[1];
    const float* b_in = (const float*)d_in[2];
    const float* w_cv = (const float*)d_in[3];
    const float* b_cv = (const float*)d_in[4];
    const float* lnw  = (const float*)d_in[5];
    const float* lnb  = (const float*)d_in[6];
    const float* w_ca = (const float*)d_in[7];
    const float* b_ca = (const float*)d_in[8];
    const float* w_sa = (const float*)d_in[9];
    const float* b_sa = (const float*)d_in[10];
    const float* w_m1 = (const float*)d_in[11];
    const float* b_m1 = (const float*)d_in[12];
    const float* w_m2 = (const float*)d_in[13];
    const float* b_m2 = (const float*)d_in[14];

    float* out_mask = (float*)d_out;                           // [B, NW, ED]
    float* ca_out   = out_mask + (size_t)B_ * NW_ * ED_;       // [B, C]
    float* sa_out   = ca_out + (size_t)B_ * C_;                // [B, H, W]

    // x_ scratch (33.5 MB) carved from the head of out_mask; bcast_kernel
    // fully overwrites it afterwards.
    float* xq = out_mask;

    char* ws = (char*)d_ws;
    double* var       = (double*)ws;                           // 256 KB
    float*  maskF     = (float*)(ws + (size_t)B_ * NW_ * 8);   // 128 KB
    float*  pooled_pp = maskF + (size_t)B_ * NW_;              // 2048*8 floats
    float*  h1 = pooled_pp + 2048 * CQ_;
    float*  h0 = h1 + EH_;
    float*  o1 = h0 + EH_;
    float*  o0 = o1 + ED_;

    pass_a<<<dim3(4, 64, B_), 256, 0, stream>>>(
        x, w_in, b_in, w_cv, b_cv, lnw, lnb, xq, var, pooled_pp);
    sa_kernel<<<dim3(8, 32, B_), 256, 0, stream>>>(xq, w_sa, b_sa, sa_out);
    k2_kernel<<<385, 256, 0, stream>>>(var, maskF, w_m1, b_m1, h1, h0,
                                       pooled_pp, w_ca, b_ca, ca_out);
    o_kernel<<<ED_ / 4, 256, 0, stream>>>(w_m2, b_m2, h1, h0, o1, o0);
    bcast_kernel<<<B_ * NW_ / 16, 256, 0, stream>>>(maskF, o1, o0, out_mask);
}

// Round 15
// 369.076 us; speedup vs baseline: 1.7047x; 1.7047x over previous
//
#include <hip/hip_runtime.h>
#include <math.h>

#define B_   8
#define C_   32
#define H_   512
#define W_   512
#define CQ_  8
#define NW_  4096          // windows per batch
#define ED_  2048
#define EH_  1024
#define EPS_ 1e-6f

#define AS1 __attribute__((address_space(1)))
#define AS3 __attribute__((address_space(3)))

__device__ __forceinline__ float leaky(float x) { return x > 0.f ? x : 0.1f * x; }
__device__ __forceinline__ float sigmoidf_(float x) { return 1.f / (1.f + __expf(-x)); }

// ---------------------------------------------------------------------------
// Preheat: stream x into L3 (268 MB vs 256 MB Infinity Cache -> ~95%
// resident). m13 copy pattern: grid-stride float4, one contiguous walk,
// tiny register state -> ~6.3 TB/s. asm sink keeps the loads live (rule #17).
// Purpose: convert pass_a's reads from loaded-HBM latency to L3-hit latency.
// ---------------------------------------------------------------------------
__global__ __launch_bounds__(256) void preheat(const float4* __restrict__ p, int n4)
{
    int i = blockIdx.x * 256 + threadIdx.x;
    const int stride = gridDim.x * 256;
    float ax = 0.f, ay = 0.f, az = 0.f, aw = 0.f;
    for (; i < n4; i += stride) {
        const float4 v = p[i];
        ax += v.x; ay += v.y; az += v.z; aw += v.w;
    }
    asm volatile("" :: "v"(ax), "v"(ay), "v"(az), "v"(aw));
}

// ---------------------------------------------------------------------------
// Pass A (r10 verbatim): wave-private depth-6 DMA ring + weights in LDS.
// grid (4, 64, 8) = 2048 blocks x 256 thr.
// ---------------------------------------------------------------------------
__global__ __launch_bounds__(256) void pass_a(
    const float* __restrict__ x,
    const float* __restrict__ w_in, const float* __restrict__ b_in,
    const float* __restrict__ w_conv, const float* __restrict__ b_conv,
    const float* __restrict__ ln_w, const float* __restrict__ ln_b,
    float* __restrict__ xq_out,                 // [B][CQ][H][W] scratch
    double* __restrict__ var_out,
    float* __restrict__ pooled_part)
{
    __shared__ float  stage[4][6][256];      // per-wave 6-slot ring (24 KB)
    __shared__ float2 s_w[CQ_ * C_];         // (w_conv, w_in) packed, 2 KB
    __shared__ float  red[4][CQ_];

    const int tid  = threadIdx.x;
    const int lane = tid & 63, wv = tid >> 6;
    const int sx   = blockIdx.x;             // cols [sx*128 .. +128), sx<4
    const int band = blockIdx.y;             // 0..63 (window row)
    const int b    = blockIdx.z;
    const size_t plane = (size_t)H_ * W_;
    const float* xb = x + (size_t)b * C_ * plane;

    // one-time weight staging (256 threads cover all 256 (q,c) pairs)
    s_w[tid] = make_float2(w_conv[tid], w_in[tid]);

    const int row0 = band * 8 + (lane >> 3);
    const int col0 = sx * 128 + wv * 32 + (lane & 7) * 4;   // <= 508
    // per-lane global source (m104/m108: src per-lane, LDS dest wave-uniform)
    const float* gw = xb + (size_t)row0 * W_ + col0;

#define STAGE(slot, c)                                                         \
    __builtin_amdgcn_global_load_lds(                                          \
        (const AS1 unsigned int*)(gw + (size_t)(c) * plane),                   \
        (AS3 unsigned int*)(&stage[wv][slot][0]), 16, 0, 0);

    float ycv[CQ_][4], yin[CQ_][4];
#pragma unroll
    for (int q = 0; q < CQ_; ++q)
#pragma unroll
        for (int j = 0; j < 4; ++j) { ycv[q][j] = 0.f; yin[q][j] = 0.f; }

    STAGE(0, 0) STAGE(1, 1) STAGE(2, 2) STAGE(3, 3) STAGE(4, 4) STAGE(5, 5)

    __syncthreads();   // weights visible to all (outside hot loop)

#pragma unroll
    for (int c = 0; c < C_; ++c) {
        // chunk c landed when outstanding <= (#chunks issued beyond c)
        if (c < 27)       asm volatile("s_waitcnt vmcnt(5)" ::: "memory");
        else if (c == 27) asm volatile("s_waitcnt vmcnt(4)" ::: "memory");
        else if (c == 28) asm volatile("s_waitcnt vmcnt(3)" ::: "memory");
        else if (c == 29) asm volatile("s_waitcnt vmcnt(2)" ::: "memory");
        else if (c == 30) asm volatile("s_waitcnt vmcnt(1)" ::: "memory");
        else              asm volatile("s_waitcnt vmcnt(0)" ::: "memory");

        const float4 v = *reinterpret_cast<const float4*>(&stage[wv][c % 6][lane * 4]);
#pragma unroll
        for (int q = 0; q < CQ_; ++q) {
            const float2 w = s_w[q * C_ + c];   // uniform-addr LDS broadcast
            const float wc = w.x, wi = w.y;
            ycv[q][0] = fmaf(wc, v.x, ycv[q][0]);
            ycv[q][1] = fmaf(wc, v.y, ycv[q][1]);
            ycv[q][2] = fmaf(wc, v.z, ycv[q][2]);
            ycv[q][3] = fmaf(wc, v.w, ycv[q][3]);
            yin[q][0] = fmaf(wi, v.x, yin[q][0]);
            yin[q][1] = fmaf(wi, v.y, yin[q][1]);
            yin[q][2] = fmaf(wi, v.z, yin[q][2]);
            yin[q][3] = fmaf(wi, v.w, yin[q][3]);
        }
        if (c + 6 < C_) {
            // slot c%6 ds_reads retired before DMA overwrites it (same wave)
            asm volatile("s_waitcnt lgkmcnt(0)" ::: "memory");
            STAGE(c % 6, c + 6)
        }
    }
#undef STAGE

    // ---- bias, LN, leaky (identical order -> identical var bits) ----
#pragma unroll
    for (int q = 0; q < CQ_; ++q) {
        const float bc = b_conv[q];
#pragma unroll
        for (int j = 0; j < 4; ++j) ycv[q][j] += bc;
    }

    float ps[CQ_];
#pragma unroll
    for (int q = 0; q < CQ_; ++q) ps[q] = 0.f;

    float xmv[4];
#pragma unroll
    for (int j = 0; j < 4; ++j) {
        float u = 0.f;
#pragma unroll
        for (int q = 0; q < CQ_; ++q) u += ycv[q][j];
        u *= 0.125f;
        float s = 0.f;
#pragma unroll
        for (int q = 0; q < CQ_; ++q) { const float d = ycv[q][j] - u; s = fmaf(d, d, s); }
        s *= 0.125f;
        const float inv = 1.f / sqrtf(s + EPS_);
        float m = 0.f;
#pragma unroll
        for (int q = 0; q < CQ_; ++q) {
            const float xv = leaky(fmaf(ln_w[q], (ycv[q][j] - u) * inv, ln_b[q]));
            ycv[q][j] = xv;          // now holds x_
            ps[q] += xv;
            m += leaky(yin[q][j] + b_in[q]);
        }
        xmv[j] = m * 0.125f;
    }

    // ---- store x_ to global (float4 per channel) ----
#pragma unroll
    for (int q = 0; q < CQ_; ++q) {
        *reinterpret_cast<float4*>(
            &xq_out[(((size_t)b * CQ_ + q) * H_ + row0) * W_ + col0]) =
            make_float4(ycv[q][0], ycv[q][1], ycv[q][2], ycv[q][3]);
    }

    // ---- window variance, fully in-register (ddof=1, double) ----
    {
        double s = (double)xmv[0] + (double)xmv[1] + (double)xmv[2] + (double)xmv[3];
        s += __shfl_xor(s, 1);
        s += __shfl_xor(s, 8);
        s += __shfl_xor(s, 16);
        s += __shfl_xor(s, 32);
        const double mean = s * (1.0 / 64.0);
        double s2 = 0.0;
#pragma unroll
        for (int j = 0; j < 4; ++j) {
            const double d = (double)xmv[j] - mean;
            s2 += d * d;
        }
        s2 += __shfl_xor(s2, 1);
        s2 += __shfl_xor(s2, 8);
        s2 += __shfl_xor(s2, 16);
        s2 += __shfl_xor(s2, 32);
        if ((lane >> 3) == 0 && (lane & 1) == 0) {          // lanes 0,2,4,6
            const int k = (lane & 7) >> 1;
            const int n = band * 64 + sx * 16 + wv * 4 + k; // <= 4095
            var_out[(size_t)b * NW_ + n] = s2 * (1.0 / 63.0);
        }
    }

    // ---- pooled partials: wave reduce -> one store per block ----
#pragma unroll
    for (int q = 0; q < CQ_; ++q) {
        float s = ps[q];
#pragma unroll
        for (int off = 32; off; off >>= 1) s += __shfl_xor(s, off);
        if (lane == 0) red[wv][q] = s;
    }
    __syncthreads();
    if (tid < CQ_) {
        const float s = red[0][tid] + red[1][tid] + red[2][tid] + red[3][tid];
        const int bid = ((int)blockIdx.z * 64 + blockIdx.y) * 4 + blockIdx.x;
        pooled_part[bid * CQ_ + tid] = s;
    }
}

// ---------------------------------------------------------------------------
// SA: 3x3 conv over x_ (from global, L3-resident) + sigmoid.
// grid (8, 32, 8), block 256. LDS tile [8][18][72] with zero-padded halo.
// ---------------------------------------------------------------------------
__global__ __launch_bounds__(256) void sa_kernel(
    const float* __restrict__ xq,
    const float* __restrict__ w_sa, const float* __restrict__ b_sa,
    float* __restrict__ sa_out)
{
    __shared__ float xl[CQ_][18][72];
    const int tid = threadIdx.x;
    const int b = blockIdx.z;
    const int ty = blockIdx.y * 16, tx = blockIdx.x * 64;

    for (int idx = tid; idx < CQ_ * 18 * 18; idx += 256) {
        const int ch = idx / 324;
        const int rem = idx % 324;
        const int r = rem / 18, c4 = rem % 18;
        const int gy = ty + r - 1;
        const int gxf = tx + c4 * 4 - 4;
        float4 v = make_float4(0.f, 0.f, 0.f, 0.f);
        if (gy >= 0 && gy < H_ && gxf >= 0 && gxf < W_)
            v = *reinterpret_cast<const float4*>(
                    &xq[(((size_t)b * CQ_ + ch) * H_ + gy) * W_ + gxf]);
        *reinterpret_cast<float4*>(&xl[ch][r][c4 * 4]) = v;
    }
    __syncthreads();

    const int px = (tid & 15) * 4, py = tid >> 4;
    const float bsa = b_sa[0];
    float acc[4] = {bsa, bsa, bsa, bsa};
#pragma unroll
    for (int q = 0; q < CQ_; ++q) {
#pragma unroll
        for (int dy = 0; dy < 3; ++dy) {
            const float* r = &xl[q][py + dy][px];
            const float4 aa = *reinterpret_cast<const float4*>(r);
            const float4 bb = *reinterpret_cast<const float4*>(r + 4);
            const float4 cc = *reinterpret_cast<const float4*>(r + 8);
            const float a[12] = {aa.x, aa.y, aa.z, aa.w, bb.x, bb.y, bb.z, bb.w,
                                 cc.x, cc.y, cc.z, cc.w};
#pragma unroll
            for (int dx = 0; dx < 3; ++dx) {
                const float w = w_sa[q * 9 + dy * 3 + dx];
#pragma unroll
                for (int j = 0; j < 4; ++j) acc[j] = fmaf(w, a[j + 3 + dx], acc[j]);
            }
        }
    }
    const float4 o = make_float4(sigmoidf_(acc[0]), sigmoidf_(acc[1]),
                                 sigmoidf_(acc[2]), sigmoidf_(acc[3]));
    *reinterpret_cast<float4*>(&sa_out[((size_t)b * H_ + (ty + py)) * W_ + tx + px]) = o;
}

// ---------------------------------------------------------------------------
// K2 (fused tail): blocks 0..127 rank, 128..383 h1/h0, 384 CA.
// ---------------------------------------------------------------------------
__global__ __launch_bounds__(256) void k2_kernel(
    const double* __restrict__ var, float* __restrict__ maskF,
    const float* __restrict__ w_m1, const float* __restrict__ b_m1,
    float* __restrict__ h1, float* __restrict__ h0,
    const float* __restrict__ pooled_part,
    const float* __restrict__ w_ca, const float* __restrict__ b_ca,
    float* __restrict__ ca_out)
{
    __shared__ double sv[NW_];   // 32 KB
    const int bi = blockIdx.x;
    const int tid = threadIdx.x;

    if (bi < 128) {
        const int b = bi >> 4;
        const double* vb = var + (size_t)b * NW_;
        for (int j = tid; j < NW_; j += 256) sv[j] = vb[j];
        __syncthreads();
        const int i = (bi & 15) * 256 + tid;
        const double vi = sv[i];
        int cnt = 0;
#pragma unroll 4
        for (int j = 0; j < NW_; ++j) {
            const double vj = sv[j];
            cnt += (vj < vi) || (vj == vi && j < i);
        }
        maskF[(size_t)b * NW_ + i] = (cnt < NW_ / 2) ? 0.f : 1.f;
    } else if (bi < 384) {
        const int wave = tid >> 6, lane = tid & 63;
        const int e = (bi - 128) * 4 + wave;
        const float* row = w_m1 + (size_t)e * ED_;
        float s = 0.f;
#pragma unroll
        for (int k = 0; k < ED_ / 64; ++k) s += row[lane + 64 * k];
#pragma unroll
        for (int off = 32; off; off >>= 1) s += __shfl_xor(s, off);
        if (lane == 0) {
            h1[e] = leaky(s + b_m1[e]);
            h0[e] = leaky(b_m1[e]);
        }
    } else {
        float* sp = (float*)sv;
        const int bq = tid >> 2, part = tid & 3;
        const int bb = bq >> 3, q = bq & 7;
        float s = 0.f;
        for (int k = part; k < 256; k += 4)
            s += pooled_part[((size_t)bb * 256 + k) * CQ_ + q];
        sp[tid] = s;
        __syncthreads();
        if (tid < 64)
            sp[256 + tid] = (sp[4 * tid] + sp[4 * tid + 1] + sp[4 * tid + 2] + sp[4 * tid + 3])
                            * (1.f / ((float)H_ * (float)W_));
        __syncthreads();
        const int ob = tid >> 5, o = tid & 31;
        float acc = b_ca[o];
#pragma unroll
        for (int qq = 0; qq < CQ_; ++qq)
            acc = fmaf(w_ca[o * CQ_ + qq], sp[256 + ob * CQ_ + qq], acc);
        ca_out[tid] = sigmoidf_(acc);
    }
}

// ---------------------------------------------------------------------------
__global__ __launch_bounds__(256) void o_kernel(const float* __restrict__ w_m2,
                                                const float* __restrict__ b_m2,
                                                const float* __restrict__ h1,
                                                const float* __restrict__ h0,
                                                float* __restrict__ o1, float* __restrict__ o0)
{
    const int wave = threadIdx.x >> 6, lane = threadIdx.x & 63;
    const int f = blockIdx.x * 4 + wave;
    const float* row = w_m2 + (size_t)f * EH_;
    float s1 = 0.f, s0 = 0.f;
#pragma unroll
    for (int k = 0; k < EH_ / 64; ++k) {
        const float w = row[lane + 64 * k];
        s1 = fmaf(w, h1[lane + 64 * k], s1);
        s0 = fmaf(w, h0[lane + 64 * k], s0);
    }
#pragma unroll
    for (int off = 32; off; off >>= 1) {
        s1 += __shfl_xor(s1, off);
        s0 += __shfl_xor(s0, off);
    }
    if (lane == 0) {
        o1[f] = s1 + b_m2[f];
        o0[f] = s0 + b_m2[f];
    }
}

// ---------------------------------------------------------------------------
__global__ __launch_bounds__(256) void bcast_kernel(const float* __restrict__ maskF,
                                                    const float* __restrict__ o1,
                                                    const float* __restrict__ o0,
                                                    float* __restrict__ out)
{
    __shared__ float sm[16];
    const int t = threadIdx.x;
    const long row0 = (long)blockIdx.x * 16;
    if (t < 16) sm[t] = maskF[row0 + t];
    const float4 a1 = ((const float4*)o1)[t], b1 = ((const float4*)o1)[t + 256];
    const float4 a0 = ((const float4*)o0)[t], b0 = ((const float4*)o0)[t + 256];
    __syncthreads();
#pragma unroll
    for (int r = 0; r < 16; ++r) {
        float4* dst = (float4*)(out + (size_t)(row0 + r) * ED_);
        const bool m = sm[r] > 0.5f;
        dst[t]       = m ? a1 : a0;
        dst[t + 256] = m ? b1 : b0;
    }
}

extern "C" void kernel_launch(void* const* d_in, const int* in_sizes, int n_in,
                              void* d_out, int out_size, void* d_ws, size_t ws_size,
                              hipStream_t stream)
{
    const float* x    = (const float*)d_in[0];
    const float* w_in = (const float*)d_in[1];
    const float* b_in = (const float*)d_in[2];
    const float* w_cv = (const float*)d_in[3];
    const float* b_cv = (const float*)d_in[4];
    const float* lnw  = (const float*)d_in[5];
    const float* lnb  = (const float*)d_in[6];
    const float* w_ca = (const float*)d_in[7];
    const float* b_ca = (const float*)d_in[8];
    const float* w_sa = (const float*)d_in[9];
    const float* b_sa = (const float*)d_in[10];
    const float* w_m1 = (const float*)d_in[11];
    const float* b_m1 = (const float*)d_in[12];
    const float* w_m2 = (const float*)d_in[13];
    const float* b_m2 = (const float*)d_in[14];

    float* out_mask = (float*)d_out;                           // [B, NW, ED]
    float* ca_out   = out_mask + (size_t)B_ * NW_ * ED_;       // [B, C]
    float* sa_out   = ca_out + (size_t)B_ * C_;                // [B, H, W]

    // x_ scratch (33.5 MB) carved from the head of out_mask; bcast_kernel
    // fully overwrites it afterwards.
    float* xq = out_mask;

    char* ws = (char*)d_ws;
    double* var       = (double*)ws;                           // 256 KB
    float*  maskF     = (float*)(ws + (size_t)B_ * NW_ * 8);   // 128 KB
    float*  pooled_pp = maskF + (size_t)B_ * NW_;              // 2048*8 floats
    float*  h1 = pooled_pp + 2048 * CQ_;
    float*  h0 = h1 + EH_;
    float*  o1 = h0 + EH_;
    float*  o0 = o1 + ED_;

    // L3 preheat of x (268 MB; ~95% fits the 256 MB Infinity Cache)
    preheat<<<2048, 256, 0, stream>>>(
        (const float4*)x, (int)((size_t)B_ * C_ * H_ * W_ / 4));
    pass_a<<<dim3(4, 64, B_), 256, 0, stream>>>(
        x, w_in, b_in, w_cv, b_cv, lnw, lnb, xq, var, pooled_pp);
    sa_kernel<<<dim3(8, 32, B_), 256, 0, stream>>>(xq, w_sa, b_sa, sa_out);
    k2_kernel<<<385, 256, 0, stream>>>(var, maskF, w_m1, b_m1, h1, h0,
                                       pooled_pp, w_ca, b_ca, ca_out);
    o_kernel<<<ED_ / 4, 256, 0, stream>>>(w_m2, b_m2, h1, h0, o1, o0);
    bcast_kernel<<<B_ * NW_ / 16, 256, 0, stream>>>(maskF, o1, o0, out_mask);
}

// Round 16
// 320.981 us; speedup vs baseline: 1.9601x; 1.1498x over previous
//
#include <hip/hip_runtime.h>
#include <math.h>

#define B_   8
#define C_   32
#define H_   512
#define W_   512
#define CQ_  8
#define NW_  4096          // windows per batch
#define ED_  2048
#define EH_  1024
#define EPS_ 1e-6f

#define AS1 __attribute__((address_space(1)))
#define AS3 __attribute__((address_space(3)))

__device__ __forceinline__ float leaky(float x) { return x > 0.f ? x : 0.1f * x; }
__device__ __forceinline__ float sigmoidf_(float x) { return 1.f / (1.f + __expf(-x)); }

// ---------------------------------------------------------------------------
// Pass A (r10 verbatim — best measured): wave-private depth-6 DMA ring +
// weights in LDS. grid (4, 64, 8) = 2048 blocks x 256 thr.
// Exhausted-axes ledger (r8..r15): deeper per-wave pipeline (DMA ring,
// asm-forced reg pipeline), higher occupancy, scalar-chain removal,
// barrier-free scheduling, and L3 preheat all leave this kernel at ~150 us —
// the NCHW 32-plane strided gather is the structural floor at HIP level.
// ---------------------------------------------------------------------------
__global__ __launch_bounds__(256) void pass_a(
    const float* __restrict__ x,
    const float* __restrict__ w_in, const float* __restrict__ b_in,
    const float* __restrict__ w_conv, const float* __restrict__ b_conv,
    const float* __restrict__ ln_w, const float* __restrict__ ln_b,
    float* __restrict__ xq_out,                 // [B][CQ][H][W] scratch
    double* __restrict__ var_out,
    float* __restrict__ pooled_part)
{
    __shared__ float  stage[4][6][256];      // per-wave 6-slot ring (24 KB)
    __shared__ float2 s_w[CQ_ * C_];         // (w_conv, w_in) packed, 2 KB
    __shared__ float  red[4][CQ_];

    const int tid  = threadIdx.x;
    const int lane = tid & 63, wv = tid >> 6;
    const int sx   = blockIdx.x;             // cols [sx*128 .. +128), sx<4
    const int band = blockIdx.y;             // 0..63 (window row)
    const int b    = blockIdx.z;
    const size_t plane = (size_t)H_ * W_;
    const float* xb = x + (size_t)b * C_ * plane;

    // one-time weight staging (256 threads cover all 256 (q,c) pairs)
    s_w[tid] = make_float2(w_conv[tid], w_in[tid]);

    const int row0 = band * 8 + (lane >> 3);
    const int col0 = sx * 128 + wv * 32 + (lane & 7) * 4;   // <= 508
    // per-lane global source (m104/m108: src per-lane, LDS dest wave-uniform)
    const float* gw = xb + (size_t)row0 * W_ + col0;

#define STAGE(slot, c)                                                         \
    __builtin_amdgcn_global_load_lds(                                          \
        (const AS1 unsigned int*)(gw + (size_t)(c) * plane),                   \
        (AS3 unsigned int*)(&stage[wv][slot][0]), 16, 0, 0);

    float ycv[CQ_][4], yin[CQ_][4];
#pragma unroll
    for (int q = 0; q < CQ_; ++q)
#pragma unroll
        for (int j = 0; j < 4; ++j) { ycv[q][j] = 0.f; yin[q][j] = 0.f; }

    STAGE(0, 0) STAGE(1, 1) STAGE(2, 2) STAGE(3, 3) STAGE(4, 4) STAGE(5, 5)

    __syncthreads();   // weights visible to all (outside hot loop)

#pragma unroll
    for (int c = 0; c < C_; ++c) {
        // chunk c landed when outstanding <= (#chunks issued beyond c)
        if (c < 27)       asm volatile("s_waitcnt vmcnt(5)" ::: "memory");
        else if (c == 27) asm volatile("s_waitcnt vmcnt(4)" ::: "memory");
        else if (c == 28) asm volatile("s_waitcnt vmcnt(3)" ::: "memory");
        else if (c == 29) asm volatile("s_waitcnt vmcnt(2)" ::: "memory");
        else if (c == 30) asm volatile("s_waitcnt vmcnt(1)" ::: "memory");
        else              asm volatile("s_waitcnt vmcnt(0)" ::: "memory");

        const float4 v = *reinterpret_cast<const float4*>(&stage[wv][c % 6][lane * 4]);
#pragma unroll
        for (int q = 0; q < CQ_; ++q) {
            const float2 w = s_w[q * C_ + c];   // uniform-addr LDS broadcast
            const float wc = w.x, wi = w.y;
            ycv[q][0] = fmaf(wc, v.x, ycv[q][0]);
            ycv[q][1] = fmaf(wc, v.y, ycv[q][1]);
            ycv[q][2] = fmaf(wc, v.z, ycv[q][2]);
            ycv[q][3] = fmaf(wc, v.w, ycv[q][3]);
            yin[q][0] = fmaf(wi, v.x, yin[q][0]);
            yin[q][1] = fmaf(wi, v.y, yin[q][1]);
            yin[q][2] = fmaf(wi, v.z, yin[q][2]);
            yin[q][3] = fmaf(wi, v.w, yin[q][3]);
        }
        if (c + 6 < C_) {
            // slot c%6 ds_reads retired before DMA overwrites it (same wave)
            asm volatile("s_waitcnt lgkmcnt(0)" ::: "memory");
            STAGE(c % 6, c + 6)
        }
    }
#undef STAGE

    // ---- bias, LN, leaky (identical order -> identical var bits) ----
#pragma unroll
    for (int q = 0; q < CQ_; ++q) {
        const float bc = b_conv[q];
#pragma unroll
        for (int j = 0; j < 4; ++j) ycv[q][j] += bc;
    }

    float ps[CQ_];
#pragma unroll
    for (int q = 0; q < CQ_; ++q) ps[q] = 0.f;

    float xmv[4];
#pragma unroll
    for (int j = 0; j < 4; ++j) {
        float u = 0.f;
#pragma unroll
        for (int q = 0; q < CQ_; ++q) u += ycv[q][j];
        u *= 0.125f;
        float s = 0.f;
#pragma unroll
        for (int q = 0; q < CQ_; ++q) { const float d = ycv[q][j] - u; s = fmaf(d, d, s); }
        s *= 0.125f;
        const float inv = 1.f / sqrtf(s + EPS_);
        float m = 0.f;
#pragma unroll
        for (int q = 0; q < CQ_; ++q) {
            const float xv = leaky(fmaf(ln_w[q], (ycv[q][j] - u) * inv, ln_b[q]));
            ycv[q][j] = xv;          // now holds x_
            ps[q] += xv;
            m += leaky(yin[q][j] + b_in[q]);
        }
        xmv[j] = m * 0.125f;
    }

    // ---- store x_ to global (float4 per channel) ----
#pragma unroll
    for (int q = 0; q < CQ_; ++q) {
        *reinterpret_cast<float4*>(
            &xq_out[(((size_t)b * CQ_ + q) * H_ + row0) * W_ + col0]) =
            make_float4(ycv[q][0], ycv[q][1], ycv[q][2], ycv[q][3]);
    }

    // ---- window variance, fully in-register (ddof=1, double) ----
    {
        double s = (double)xmv[0] + (double)xmv[1] + (double)xmv[2] + (double)xmv[3];
        s += __shfl_xor(s, 1);
        s += __shfl_xor(s, 8);
        s += __shfl_xor(s, 16);
        s += __shfl_xor(s, 32);
        const double mean = s * (1.0 / 64.0);
        double s2 = 0.0;
#pragma unroll
        for (int j = 0; j < 4; ++j) {
            const double d = (double)xmv[j] - mean;
            s2 += d * d;
        }
        s2 += __shfl_xor(s2, 1);
        s2 += __shfl_xor(s2, 8);
        s2 += __shfl_xor(s2, 16);
        s2 += __shfl_xor(s2, 32);
        if ((lane >> 3) == 0 && (lane & 1) == 0) {          // lanes 0,2,4,6
            const int k = (lane & 7) >> 1;
            const int n = band * 64 + sx * 16 + wv * 4 + k; // <= 4095
            var_out[(size_t)b * NW_ + n] = s2 * (1.0 / 63.0);
        }
    }

    // ---- pooled partials: wave reduce -> one store per block ----
#pragma unroll
    for (int q = 0; q < CQ_; ++q) {
        float s = ps[q];
#pragma unroll
        for (int off = 32; off; off >>= 1) s += __shfl_xor(s, off);
        if (lane == 0) red[wv][q] = s;
    }
    __syncthreads();
    if (tid < CQ_) {
        const float s = red[0][tid] + red[1][tid] + red[2][tid] + red[3][tid];
        const int bid = ((int)blockIdx.z * 64 + blockIdx.y) * 4 + blockIdx.x;
        pooled_part[bid * CQ_ + tid] = s;
    }
}

// ---------------------------------------------------------------------------
// SA: 3x3 conv over x_ (from global, L3-resident) + sigmoid.
// grid (8, 32, 8), block 256. LDS tile [8][18][72] with zero-padded halo.
// ---------------------------------------------------------------------------
__global__ __launch_bounds__(256) void sa_kernel(
    const float* __restrict__ xq,
    const float* __restrict__ w_sa, const float* __restrict__ b_sa,
    float* __restrict__ sa_out)
{
    __shared__ float xl[CQ_][18][72];
    const int tid = threadIdx.x;
    const int b = blockIdx.z;
    const int ty = blockIdx.y * 16, tx = blockIdx.x * 64;

    for (int idx = tid; idx < CQ_ * 18 * 18; idx += 256) {
        const int ch = idx / 324;
        const int rem = idx % 324;
        const int r = rem / 18, c4 = rem % 18;
        const int gy = ty + r - 1;
        const int gxf = tx + c4 * 4 - 4;
        float4 v = make_float4(0.f, 0.f, 0.f, 0.f);
        if (gy >= 0 && gy < H_ && gxf >= 0 && gxf < W_)
            v = *reinterpret_cast<const float4*>(
                    &xq[(((size_t)b * CQ_ + ch) * H_ + gy) * W_ + gxf]);
        *reinterpret_cast<float4*>(&xl[ch][r][c4 * 4]) = v;
    }
    __syncthreads();

    const int px = (tid & 15) * 4, py = tid >> 4;
    const float bsa = b_sa[0];
    float acc[4] = {bsa, bsa, bsa, bsa};
#pragma unroll
    for (int q = 0; q < CQ_; ++q) {
#pragma unroll
        for (int dy = 0; dy < 3; ++dy) {
            const float* r = &xl[q][py + dy][px];
            const float4 aa = *reinterpret_cast<const float4*>(r);
            const float4 bb = *reinterpret_cast<const float4*>(r + 4);
            const float4 cc = *reinterpret_cast<const float4*>(r + 8);
            const float a[12] = {aa.x, aa.y, aa.z, aa.w, bb.x, bb.y, bb.z, bb.w,
                                 cc.x, cc.y, cc.z, cc.w};
#pragma unroll
            for (int dx = 0; dx < 3; ++dx) {
                const float w = w_sa[q * 9 + dy * 3 + dx];
#pragma unroll
                for (int j = 0; j < 4; ++j) acc[j] = fmaf(w, a[j + 3 + dx], acc[j]);
            }
        }
    }
    const float4 o = make_float4(sigmoidf_(acc[0]), sigmoidf_(acc[1]),
                                 sigmoidf_(acc[2]), sigmoidf_(acc[3]));
    *reinterpret_cast<float4*>(&sa_out[((size_t)b * H_ + (ty + py)) * W_ + tx + px]) = o;
}

// ---------------------------------------------------------------------------
// K2 (fused tail): blocks 0..127 rank, 128..383 h1/h0, 384 CA.
// ---------------------------------------------------------------------------
__global__ __launch_bounds__(256) void k2_kernel(
    const double* __restrict__ var, float* __restrict__ maskF,
    const float* __restrict__ w_m1, const float* __restrict__ b_m1,
    float* __restrict__ h1, float* __restrict__ h0,
    const float* __restrict__ pooled_part,
    const float* __restrict__ w_ca, const float* __restrict__ b_ca,
    float* __restrict__ ca_out)
{
    __shared__ double sv[NW_];   // 32 KB
    const int bi = blockIdx.x;
    const int tid = threadIdx.x;

    if (bi < 128) {
        const int b = bi >> 4;
        const double* vb = var + (size_t)b * NW_;
        for (int j = tid; j < NW_; j += 256) sv[j] = vb[j];
        __syncthreads();
        const int i = (bi & 15) * 256 + tid;
        const double vi = sv[i];
        int cnt = 0;
#pragma unroll 4
        for (int j = 0; j < NW_; ++j) {
            const double vj = sv[j];
            cnt += (vj < vi) || (vj == vi && j < i);
        }
        maskF[(size_t)b * NW_ + i] = (cnt < NW_ / 2) ? 0.f : 1.f;
    } else if (bi < 384) {
        const int wave = tid >> 6, lane = tid & 63;
        const int e = (bi - 128) * 4 + wave;
        const float* row = w_m1 + (size_t)e * ED_;
        float s = 0.f;
#pragma unroll
        for (int k = 0; k < ED_ / 64; ++k) s += row[lane + 64 * k];
#pragma unroll
        for (int off = 32; off; off >>= 1) s += __shfl_xor(s, off);
        if (lane == 0) {
            h1[e] = leaky(s + b_m1[e]);
            h0[e] = leaky(b_m1[e]);
        }
    } else {
        float* sp = (float*)sv;
        const int bq = tid >> 2, part = tid & 3;
        const int bb = bq >> 3, q = bq & 7;
        float s = 0.f;
        for (int k = part; k < 256; k += 4)
            s += pooled_part[((size_t)bb * 256 + k) * CQ_ + q];
        sp[tid] = s;
        __syncthreads();
        if (tid < 64)
            sp[256 + tid] = (sp[4 * tid] + sp[4 * tid + 1] + sp[4 * tid + 2] + sp[4 * tid + 3])
                            * (1.f / ((float)H_ * (float)W_));
        __syncthreads();
        const int ob = tid >> 5, o = tid & 31;
        float acc = b_ca[o];
#pragma unroll
        for (int qq = 0; qq < CQ_; ++qq)
            acc = fmaf(w_ca[o * CQ_ + qq], sp[256 + ob * CQ_ + qq], acc);
        ca_out[tid] = sigmoidf_(acc);
    }
}

// ---------------------------------------------------------------------------
__global__ __launch_bounds__(256) void o_kernel(const float* __restrict__ w_m2,
                                                const float* __restrict__ b_m2,
                                                const float* __restrict__ h1,
                                                const float* __restrict__ h0,
                                                float* __restrict__ o1, float* __restrict__ o0)
{
    const int wave = threadIdx.x >> 6, lane = threadIdx.x & 63;
    const int f = blockIdx.x * 4 + wave;
    const float* row = w_m2 + (size_t)f * EH_;
    float s1 = 0.f, s0 = 0.f;
#pragma unroll
    for (int k = 0; k < EH_ / 64; ++k) {
        const float w = row[lane + 64 * k];
        s1 = fmaf(w, h1[lane + 64 * k], s1);
        s0 = fmaf(w, h0[lane + 64 * k], s0);
    }
#pragma unroll
    for (int off = 32; off; off >>= 1) {
        s1 += __shfl_xor(s1, off);
        s0 += __shfl_xor(s0, off);
    }
    if (lane == 0) {
        o1[f] = s1 + b_m2[f];
        o0[f] = s0 + b_m2[f];
    }
}

// ---------------------------------------------------------------------------
__global__ __launch_bounds__(256) void bcast_kernel(const float* __restrict__ maskF,
                                                    const float* __restrict__ o1,
                                                    const float* __restrict__ o0,
                                                    float* __restrict__ out)
{
    __shared__ float sm[16];
    const int t = threadIdx.x;
    const long row0 = (long)blockIdx.x * 16;
    if (t < 16) sm[t] = maskF[row0 + t];
    const float4 a1 = ((const float4*)o1)[t], b1 = ((const float4*)o1)[t + 256];
    const float4 a0 = ((const float4*)o0)[t], b0 = ((const float4*)o0)[t + 256];
    __syncthreads();
#pragma unroll
    for (int r = 0; r < 16; ++r) {
        float4* dst = (float4*)(out + (size_t)(row0 + r) * ED_);
        const bool m = sm[r] > 0.5f;
        dst[t]       = m ? a1 : a0;
        dst[t + 256] = m ? b1 : b0;
    }
}

extern "C" void kernel_launch(void* const* d_in, const int* in_sizes, int n_in,
                              void* d_out, int out_size, void* d_ws, size_t ws_size,
                              hipStream_t stream)
{
    const float* x    = (const float*)d_in[0];
    const float* w_in = (const float*)d_in[1];
    const float* b_in = (const float*)d_in[2];
    const float* w_cv = (const float*)d_in[3];
    const float* b_cv = (const float*)d_in[4];
    const float* lnw  = (const float*)d_in[5];
    const float* lnb  = (const float*)d_in[6];
    const float* w_ca = (const float*)d_in[7];
    const float* b_ca = (const float*)d_in[8];
    const float* w_sa = (const float*)d_in[9];
    const float* b_sa = (const float*)d_in[10];
    const float* w_m1 = (const float*)d_in[11];
    const float* b_m1 = (const float*)d_in[12];
    const float* w_m2 = (const float*)d_in[13];
    const float* b_m2 = (const float*)d_in[14];

    float* out_mask = (float*)d_out;                           // [B, NW, ED]
    float* ca_out   = out_mask + (size_t)B_ * NW_ * ED_;       // [B, C]
    float* sa_out   = ca_out + (size_t)B_ * C_;                // [B, H, W]

    // x_ scratch (33.5 MB) carved from the head of out_mask; bcast_kernel
    // fully overwrites it afterwards.
    float* xq = out_mask;

    char* ws = (char*)d_ws;
    double* var       = (double*)ws;                           // 256 KB
    float*  maskF     = (float*)(ws + (size_t)B_ * NW_ * 8);   // 128 KB
    float*  pooled_pp = maskF + (size_t)B_ * NW_;              // 2048*8 floats
    float*  h1 = pooled_pp + 2048 * CQ_;
    float*  h0 = h1 + EH_;
    float*  o1 = h0 + EH_;
    float*  o0 = o1 + ED_;

    pass_a<<<dim3(4, 64, B_), 256, 0, stream>>>(
        x, w_in, b_in, w_cv, b_cv, lnw, lnb, xq, var, pooled_pp);
    sa_kernel<<<dim3(8, 32, B_), 256, 0, stream>>>(xq, w_sa, b_sa, sa_out);
    k2_kernel<<<385, 256, 0, stream>>>(var, maskF, w_m1, b_m1, h1, h0,
                                       pooled_pp, w_ca, b_ca, ca_out);
    o_kernel<<<ED_ / 4, 256, 0, stream>>>(w_m2, b_m2, h1, h0, o1, o0);
    bcast_kernel<<<B_ * NW_ / 16, 256, 0, stream>>>(maskF, o1, o0, out_mask);
}